// Round 1
// baseline (2083.606 us; speedup 1.0000x reference)
//
#include <hip/hip_runtime.h>

#define TS 524288u
#define NL 16
#define FSTR (TS * 16u)   // 8388608 — stride between feat0 and feat1 rows

// SCALINGS = floor(16 * growth^l), growth = 2^(7/15). Standard NGP ladder.
__device__ const float SCAL[16] = {
    16.f, 22.f, 30.f, 42.f, 58.f, 80.f, 111.f, 153.f,
    212.f, 294.f, 406.f, 561.f, 776.f, 1072.f, 1482.f, 2048.f
};

__global__ __launch_bounds__(256) void hashenc_kernel(
    const float* __restrict__ x,
    const float* __restrict__ tab,
    float2* __restrict__ out)
{
    const unsigned tid = blockIdx.x * 256u + threadIdx.x;
    const unsigned n = tid >> 4;      // point index
    const unsigned l = tid & 15u;     // level index

    // 16 consecutive lanes share a point -> these are broadcast loads (L1 hit)
    const float x0 = x[3u * n + 0u];
    const float x1 = x[3u * n + 1u];
    const float x2 = x[3u * n + 2u];

    // ---- hash vertex coords at level l ----
    const float S = SCAL[l];
    const float s0 = x0 * S, s1 = x1 * S, s2 = x2 * S;
    const unsigned A0 = (unsigned)(int)ceilf(s0);
    const unsigned B0 = (unsigned)(int)floorf(s0);
    const unsigned A1 = (unsigned)(int)ceilf(s1) * 2654435761u;
    const unsigned B1 = (unsigned)(int)floorf(s1) * 2654435761u;
    const unsigned A2 = (unsigned)(int)ceilf(s2) * 805459861u;
    const unsigned B2 = (unsigned)(int)floorf(s2) * 805459861u;

    const unsigned m = TS - 1u;
    const unsigned base = l * TS;
    // SEL order: (1,1,1),(1,1,0),(1,0,1),(0,1,1),(1,0,0),(0,1,0),(0,0,1),(0,0,0)
    const unsigned i0 = ((A0 ^ A1 ^ A2) & m) + base;
    const unsigned i1 = ((A0 ^ A1 ^ B2) & m) + base;
    const unsigned i2 = ((A0 ^ B1 ^ A2) & m) + base;
    const unsigned i3 = ((B0 ^ A1 ^ A2) & m) + base;
    const unsigned i4 = ((A0 ^ B1 ^ B2) & m) + base;
    const unsigned i5 = ((B0 ^ A1 ^ B2) & m) + base;
    const unsigned i6 = ((B0 ^ B1 ^ A2) & m) + base;
    const unsigned i7 = ((B0 ^ B1 ^ B2) & m) + base;

    // 16 independent gathers — issue all before use for MLP
    const float a0 = tab[i0];
    const float a1 = tab[i1];
    const float a2 = tab[i2];
    const float a3 = tab[i3];
    const float a4 = tab[i4];
    const float a5 = tab[i5];
    const float a6 = tab[i6];
    const float a7 = tab[i7];
    const float b0 = tab[i0 + FSTR];
    const float b1 = tab[i1 + FSTR];
    const float b2 = tab[i2 + FSTR];
    const float b3 = tab[i3 + FSTR];
    const float b4 = tab[i4 + FSTR];
    const float b5 = tab[i5 + FSTR];
    const float b6 = tab[i6 + FSTR];
    const float b7 = tab[i7 + FSTR];

    // ---- weights: reference's reshape bug. po[n,i,l] = frac[n,(i*16+l)/3,(i*16+l)%3]
    float wa, wb, wc;
    {
        const unsigned k = l;            // px
        const unsigned lev = k / 3u, dim = k - 3u * (k / 3u);
        const float xv = (dim == 0u) ? x0 : ((dim == 1u) ? x1 : x2);
        const float t = xv * SCAL[lev];
        wa = t - floorf(t);
    }
    {
        const unsigned k = l + 16u;      // py
        const unsigned lev = k / 3u, dim = k - 3u * (k / 3u);
        const float xv = (dim == 0u) ? x0 : ((dim == 1u) ? x1 : x2);
        const float t = xv * SCAL[lev];
        wb = t - floorf(t);
    }
    {
        const unsigned k = l + 32u;      // pz
        const unsigned lev = k / 3u, dim = k - 3u * (k / 3u);
        const float xv = (dim == 0u) ? x0 : ((dim == 1u) ? x1 : x2);
        const float t = xv * SCAL[lev];
        wc = t - floorf(t);
    }
    const float qa = 1.f - wa, qb = 1.f - wb, qc = 1.f - wc;

    // ---- trilinear combine (reference order) ----
    // f03 = F0*px + F3*(1-px); f12 = F1*px + F2*(1-px)
    // f56 = F5*px + F6*(1-px); f47 = F4*px + F7*(1-px)
    // enc = (f03*py + f12*(1-py))*pz + (f47*py + f56*(1-py))*(1-pz)
    const float e0 = ((a0 * wa + a3 * qa) * wb + (a1 * wa + a2 * qa) * qb) * wc
                   + ((a4 * wa + a7 * qa) * wb + (a5 * wa + a6 * qa) * qb) * qc;
    const float e1 = ((b0 * wa + b3 * qa) * wb + (b1 * wa + b2 * qa) * qb) * wc
                   + ((b4 * wa + b7 * qa) * wb + (b5 * wa + b6 * qa) * qb) * qc;

    out[tid] = make_float2(e0, e1);
}

extern "C" void kernel_launch(void* const* d_in, const int* in_sizes, int n_in,
                              void* d_out, int out_size, void* d_ws, size_t ws_size,
                              hipStream_t stream) {
    const float* x   = (const float*)d_in[0];
    const float* tab = (const float*)d_in[1];
    float2* out = (float2*)d_out;
    const int npts = in_sizes[0] / 3;          // 1048576
    const int total = npts * 16;               // one thread per (point, level)
    hashenc_kernel<<<total / 256, 256, 0, stream>>>(x, tab, out);
}

// Round 2
// 828.623 us; speedup vs baseline: 2.5145x; 2.5145x over previous
//
#include <hip/hip_runtime.h>

#define TS 524288u
#define FSTR (TS * 16u)   // 8388608 entries per feature row

// SCALINGS = floor(16 * growth^l), growth = 2^(7/15).
__device__ const float SCAL[16] = {
    16.f, 22.f, 30.f, 42.f, 58.f, 80.f, 111.f, 153.f,
    212.f, 294.f, 406.f, 561.f, 776.f, 1072.f, 1482.f, 2048.f
};

// ---- pass 1: interleave the two feature rows into float2[8388608] in ws ----
__global__ __launch_bounds__(256) void relayout_kernel(
    const float* __restrict__ tab, float2* __restrict__ t2)
{
    const unsigned i = (blockIdx.x * 256u + threadIdx.x) * 4u; // entry index
    const float4 a = *reinterpret_cast<const float4*>(tab + i);
    const float4 b = *reinterpret_cast<const float4*>(tab + i + FSTR);
    float4* dst = reinterpret_cast<float4*>(t2 + i);
    dst[0] = make_float4(a.x, b.x, a.y, b.y);
    dst[1] = make_float4(a.z, b.z, a.w, b.w);
}

// ---- pass 2: gather + trilerp. One block = 256 points at ONE level.
// Level changes every 4096 blocks so the (roughly in-order) dispatcher keeps
// only ~1 level slice (4 MB) hot in the L2s at any time.
__global__ __launch_bounds__(256) void hashenc_kernel(
    const float* __restrict__ x,
    const float2* __restrict__ t2,
    float2* __restrict__ out)
{
    const unsigned lv = blockIdx.x >> 12;          // 0..15, uniform per block
    const unsigned pg = blockIdx.x & 4095u;
    const unsigned n  = pg * 256u + threadIdx.x;   // point index

    const float x0 = x[3u * n + 0u];
    const float x1 = x[3u * n + 1u];
    const float x2 = x[3u * n + 2u];

    // ---- hash vertex coords at level lv ----
    const float S = SCAL[lv];
    const float s0 = x0 * S, s1 = x1 * S, s2 = x2 * S;
    const unsigned A0 = (unsigned)(int)ceilf(s0);
    const unsigned B0 = (unsigned)(int)floorf(s0);
    const unsigned A1 = (unsigned)(int)ceilf(s1) * 2654435761u;
    const unsigned B1 = (unsigned)(int)floorf(s1) * 2654435761u;
    const unsigned A2 = (unsigned)(int)ceilf(s2) * 805459861u;
    const unsigned B2 = (unsigned)(int)floorf(s2) * 805459861u;

    const unsigned m = TS - 1u;
    const unsigned base = lv * TS;
    // SEL order: (1,1,1),(1,1,0),(1,0,1),(0,1,1),(1,0,0),(0,1,0),(0,0,1),(0,0,0)
    const unsigned i0 = ((A0 ^ A1 ^ A2) & m) + base;
    const unsigned i1 = ((A0 ^ A1 ^ B2) & m) + base;
    const unsigned i2 = ((A0 ^ B1 ^ A2) & m) + base;
    const unsigned i3 = ((B0 ^ A1 ^ A2) & m) + base;
    const unsigned i4 = ((A0 ^ B1 ^ B2) & m) + base;
    const unsigned i5 = ((B0 ^ A1 ^ B2) & m) + base;
    const unsigned i6 = ((B0 ^ B1 ^ A2) & m) + base;
    const unsigned i7 = ((B0 ^ B1 ^ B2) & m) + base;

    const float2 v0 = t2[i0];
    const float2 v1 = t2[i1];
    const float2 v2 = t2[i2];
    const float2 v3 = t2[i3];
    const float2 v4 = t2[i4];
    const float2 v5 = t2[i5];
    const float2 v6 = t2[i6];
    const float2 v7 = t2[i7];

    // ---- weights: reference reshape quirk. po[n,i,l] = frac[n,(i*16+l)/3,(i*16+l)%3]
    float w[3];
#pragma unroll
    for (int i = 0; i < 3; ++i) {
        const unsigned k = lv + 16u * i;          // block-uniform
        const unsigned lev = k / 3u, dim = k % 3u;
        const float xv = (dim == 0u) ? x0 : ((dim == 1u) ? x1 : x2);
        const float t = xv * SCAL[lev];
        w[i] = t - floorf(t);
    }
    const float wa = w[0], wb = w[1], wc = w[2];
    const float qa = 1.f - wa, qb = 1.f - wb, qc = 1.f - wc;

    const float e0 = ((v0.x * wa + v3.x * qa) * wb + (v1.x * wa + v2.x * qa) * qb) * wc
                   + ((v4.x * wa + v7.x * qa) * wb + (v5.x * wa + v6.x * qa) * qb) * qc;
    const float e1 = ((v0.y * wa + v3.y * qa) * wb + (v1.y * wa + v2.y * qa) * qb) * wc
                   + ((v4.y * wa + v7.y * qa) * wb + (v5.y * wa + v6.y * qa) * qb) * qc;

    out[n * 16u + lv] = make_float2(e0, e1);
}

// ---- fallback (round-1 kernel) if ws is too small for the relayout ----
__global__ __launch_bounds__(256) void hashenc_fallback(
    const float* __restrict__ x,
    const float* __restrict__ tab,
    float2* __restrict__ out)
{
    const unsigned tid = blockIdx.x * 256u + threadIdx.x;
    const unsigned n = tid >> 4;
    const unsigned l = tid & 15u;
    const float x0 = x[3u * n], x1 = x[3u * n + 1u], x2 = x[3u * n + 2u];
    const float S = SCAL[l];
    const float s0 = x0 * S, s1 = x1 * S, s2 = x2 * S;
    const unsigned A0 = (unsigned)(int)ceilf(s0);
    const unsigned B0 = (unsigned)(int)floorf(s0);
    const unsigned A1 = (unsigned)(int)ceilf(s1) * 2654435761u;
    const unsigned B1 = (unsigned)(int)floorf(s1) * 2654435761u;
    const unsigned A2 = (unsigned)(int)ceilf(s2) * 805459861u;
    const unsigned B2 = (unsigned)(int)floorf(s2) * 805459861u;
    const unsigned m = TS - 1u;
    const unsigned base = l * TS;
    const unsigned i0 = ((A0 ^ A1 ^ A2) & m) + base;
    const unsigned i1 = ((A0 ^ A1 ^ B2) & m) + base;
    const unsigned i2 = ((A0 ^ B1 ^ A2) & m) + base;
    const unsigned i3 = ((B0 ^ A1 ^ A2) & m) + base;
    const unsigned i4 = ((A0 ^ B1 ^ B2) & m) + base;
    const unsigned i5 = ((B0 ^ A1 ^ B2) & m) + base;
    const unsigned i6 = ((B0 ^ B1 ^ A2) & m) + base;
    const unsigned i7 = ((B0 ^ B1 ^ B2) & m) + base;
    const float a0 = tab[i0], a1 = tab[i1], a2 = tab[i2], a3 = tab[i3];
    const float a4 = tab[i4], a5 = tab[i5], a6 = tab[i6], a7 = tab[i7];
    const float b0 = tab[i0 + FSTR], b1 = tab[i1 + FSTR], b2 = tab[i2 + FSTR], b3 = tab[i3 + FSTR];
    const float b4 = tab[i4 + FSTR], b5 = tab[i5 + FSTR], b6 = tab[i6 + FSTR], b7 = tab[i7 + FSTR];
    float w[3];
#pragma unroll
    for (int i = 0; i < 3; ++i) {
        const unsigned k = l + 16u * i;
        const unsigned lev = k / 3u, dim = k % 3u;
        const float xv = (dim == 0u) ? x0 : ((dim == 1u) ? x1 : x2);
        const float t = xv * SCAL[lev];
        w[i] = t - floorf(t);
    }
    const float wa = w[0], wb = w[1], wc = w[2];
    const float qa = 1.f - wa, qb = 1.f - wb, qc = 1.f - wc;
    const float e0 = ((a0 * wa + a3 * qa) * wb + (a1 * wa + a2 * qa) * qb) * wc
                   + ((a4 * wa + a7 * qa) * wb + (a5 * wa + a6 * qa) * qb) * qc;
    const float e1 = ((b0 * wa + b3 * qa) * wb + (b1 * wa + b2 * qa) * qb) * wc
                   + ((b4 * wa + b7 * qa) * wb + (b5 * wa + b6 * qa) * qb) * qc;
    out[tid] = make_float2(e0, e1);
}

extern "C" void kernel_launch(void* const* d_in, const int* in_sizes, int n_in,
                              void* d_out, int out_size, void* d_ws, size_t ws_size,
                              hipStream_t stream) {
    const float* x   = (const float*)d_in[0];
    const float* tab = (const float*)d_in[1];
    float2* out = (float2*)d_out;

    const size_t needed = (size_t)FSTR * sizeof(float2);   // 64 MB
    if (ws_size >= needed) {
        float2* t2 = (float2*)d_ws;
        relayout_kernel<<<FSTR / 4u / 256u, 256, 0, stream>>>(tab, t2);
        hashenc_kernel<<<16 * 4096, 256, 0, stream>>>(x, t2, out);
    } else {
        const int npts = in_sizes[0] / 3;
        hashenc_fallback<<<npts * 16 / 256, 256, 0, stream>>>(x, tab, out);
    }
}

// Round 3
// 728.264 us; speedup vs baseline: 2.8611x; 1.1378x over previous
//
#include <hip/hip_runtime.h>

#define TS 524288u
#define NENT (TS * 16u)    // 8388608 entries per feature row
#define FSTR NENT
#define NPTS 1048576u

// SCALINGS = floor(16 * growth^l), growth = 2^(7/15).
__device__ const float SCAL[16] = {
    16.f, 22.f, 30.f, 42.f, 58.f, 80.f, 111.f, 153.f,
    212.f, 294.f, 406.f, 561.f, 776.f, 1072.f, 1482.f, 2048.f
};

// fp32 -> bf16 with round-to-nearest-even
__device__ inline unsigned bfp(float f) {
    unsigned u = __float_as_uint(f);
    return (u + 0x7FFFu + ((u >> 16) & 1u)) >> 16;
}

// ---- pass 1: pack the two fp32 feature rows into bf16x2 (4B/entry) ----
__global__ __launch_bounds__(256) void pack_kernel(
    const float* __restrict__ tab, unsigned* __restrict__ tp)
{
    const unsigned i = (blockIdx.x * 256u + threadIdx.x) * 4u;
    const float4 a = *reinterpret_cast<const float4*>(tab + i);         // feat0
    const float4 b = *reinterpret_cast<const float4*>(tab + i + FSTR);  // feat1
    uint4 r;
    r.x = bfp(a.x) | (bfp(b.x) << 16);
    r.y = bfp(a.y) | (bfp(b.y) << 16);
    r.z = bfp(a.z) | (bfp(b.z) << 16);
    r.w = bfp(a.w) | (bfp(b.w) << 16);
    *reinterpret_cast<uint4*>(tp + i) = r;
}

// unpack bf16 pair
__device__ inline float blo(unsigned g) { return __uint_as_float(g << 16); }
__device__ inline float bhi(unsigned g) { return __uint_as_float(g & 0xFFFF0000u); }

// ---- pass 2: gather + trilerp. One block = 256 points at ONE level.
// DIRECT=false: write level-major scratch enc[lv][n] (coalesced).
// DIRECT=true : write out[n*16+lv] directly (strided fallback).
template <bool DIRECT>
__global__ __launch_bounds__(256) void gather_kernel(
    const float* __restrict__ x,
    const unsigned* __restrict__ tp,
    float2* __restrict__ dst)
{
    const unsigned lv = blockIdx.x >> 12;          // 0..15, uniform per block
    const unsigned n  = (blockIdx.x & 4095u) * 256u + threadIdx.x;

    const float x0 = x[3u * n + 0u];
    const float x1 = x[3u * n + 1u];
    const float x2 = x[3u * n + 2u];

    const float S = SCAL[lv];
    const float s0 = x0 * S, s1 = x1 * S, s2 = x2 * S;
    const unsigned A0 = (unsigned)(int)ceilf(s0);
    const unsigned B0 = (unsigned)(int)floorf(s0);
    const unsigned A1 = (unsigned)(int)ceilf(s1) * 2654435761u;
    const unsigned B1 = (unsigned)(int)floorf(s1) * 2654435761u;
    const unsigned A2 = (unsigned)(int)ceilf(s2) * 805459861u;
    const unsigned B2 = (unsigned)(int)floorf(s2) * 805459861u;

    const unsigned m = TS - 1u;
    const unsigned base = lv * TS;
    // SEL order: (1,1,1),(1,1,0),(1,0,1),(0,1,1),(1,0,0),(0,1,0),(0,0,1),(0,0,0)
    const unsigned i0 = ((A0 ^ A1 ^ A2) & m) + base;
    const unsigned i1 = ((A0 ^ A1 ^ B2) & m) + base;
    const unsigned i2 = ((A0 ^ B1 ^ A2) & m) + base;
    const unsigned i3 = ((B0 ^ A1 ^ A2) & m) + base;
    const unsigned i4 = ((A0 ^ B1 ^ B2) & m) + base;
    const unsigned i5 = ((B0 ^ A1 ^ B2) & m) + base;
    const unsigned i6 = ((B0 ^ B1 ^ A2) & m) + base;
    const unsigned i7 = ((B0 ^ B1 ^ B2) & m) + base;

    const unsigned g0 = tp[i0];
    const unsigned g1 = tp[i1];
    const unsigned g2 = tp[i2];
    const unsigned g3 = tp[i3];
    const unsigned g4 = tp[i4];
    const unsigned g5 = tp[i5];
    const unsigned g6 = tp[i6];
    const unsigned g7 = tp[i7];

    // weights: reference reshape quirk. po[n,i,l] = frac[n,(i*16+l)/3,(i*16+l)%3]
    float w[3];
#pragma unroll
    for (int i = 0; i < 3; ++i) {
        const unsigned k = lv + 16u * i;          // block-uniform
        const unsigned lev = k / 3u, dim = k % 3u;
        const float xv = (dim == 0u) ? x0 : ((dim == 1u) ? x1 : x2);
        const float t = xv * SCAL[lev];
        w[i] = t - floorf(t);
    }
    const float wa = w[0], wb = w[1], wc = w[2];
    const float qa = 1.f - wa, qb = 1.f - wb, qc = 1.f - wc;

    const float e0 = ((blo(g0) * wa + blo(g3) * qa) * wb + (blo(g1) * wa + blo(g2) * qa) * qb) * wc
                   + ((blo(g4) * wa + blo(g7) * qa) * wb + (blo(g5) * wa + blo(g6) * qa) * qb) * qc;
    const float e1 = ((bhi(g0) * wa + bhi(g3) * qa) * wb + (bhi(g1) * wa + bhi(g2) * qa) * qb) * wc
                   + ((bhi(g4) * wa + bhi(g7) * qa) * wb + (bhi(g5) * wa + bhi(g6) * qa) * qb) * qc;

    if (DIRECT)
        dst[n * 16u + lv] = make_float2(e0, e1);
    else
        dst[lv * NPTS + n] = make_float2(e0, e1);
}

// ---- pass 3: transpose enc[lv][n] -> out[n][lv]. Per-thread: 16 coalesced
// reads (across lanes), 128B contiguous write.
__global__ __launch_bounds__(256) void transpose_kernel(
    const float2* __restrict__ enc, float4* __restrict__ out)
{
    const unsigned n = blockIdx.x * 256u + threadIdx.x;
    float2 v[16];
#pragma unroll
    for (int lv = 0; lv < 16; ++lv) v[lv] = enc[lv * NPTS + n];
#pragma unroll
    for (int k = 0; k < 8; ++k)
        out[n * 8u + k] = make_float4(v[2 * k].x, v[2 * k].y, v[2 * k + 1].x, v[2 * k + 1].y);
}

// ---- last-resort fallback: no workspace use (round-1 kernel) ----
__global__ __launch_bounds__(256) void hashenc_fallback(
    const float* __restrict__ x,
    const float* __restrict__ tab,
    float2* __restrict__ out)
{
    const unsigned tid = blockIdx.x * 256u + threadIdx.x;
    const unsigned n = tid >> 4;
    const unsigned l = tid & 15u;
    const float x0 = x[3u * n], x1 = x[3u * n + 1u], x2 = x[3u * n + 2u];
    const float S = SCAL[l];
    const float s0 = x0 * S, s1 = x1 * S, s2 = x2 * S;
    const unsigned A0 = (unsigned)(int)ceilf(s0);
    const unsigned B0 = (unsigned)(int)floorf(s0);
    const unsigned A1 = (unsigned)(int)ceilf(s1) * 2654435761u;
    const unsigned B1 = (unsigned)(int)floorf(s1) * 2654435761u;
    const unsigned A2 = (unsigned)(int)ceilf(s2) * 805459861u;
    const unsigned B2 = (unsigned)(int)floorf(s2) * 805459861u;
    const unsigned m = TS - 1u;
    const unsigned base = l * TS;
    const unsigned i0 = ((A0 ^ A1 ^ A2) & m) + base;
    const unsigned i1 = ((A0 ^ A1 ^ B2) & m) + base;
    const unsigned i2 = ((A0 ^ B1 ^ A2) & m) + base;
    const unsigned i3 = ((B0 ^ A1 ^ A2) & m) + base;
    const unsigned i4 = ((A0 ^ B1 ^ B2) & m) + base;
    const unsigned i5 = ((B0 ^ A1 ^ B2) & m) + base;
    const unsigned i6 = ((B0 ^ B1 ^ A2) & m) + base;
    const unsigned i7 = ((B0 ^ B1 ^ B2) & m) + base;
    const float a0 = tab[i0], a1 = tab[i1], a2 = tab[i2], a3 = tab[i3];
    const float a4 = tab[i4], a5 = tab[i5], a6 = tab[i6], a7 = tab[i7];
    const float b0 = tab[i0 + FSTR], b1 = tab[i1 + FSTR], b2 = tab[i2 + FSTR], b3 = tab[i3 + FSTR];
    const float b4 = tab[i4 + FSTR], b5 = tab[i5 + FSTR], b6 = tab[i6 + FSTR], b7 = tab[i7 + FSTR];
    float w[3];
#pragma unroll
    for (int i = 0; i < 3; ++i) {
        const unsigned k = l + 16u * i;
        const unsigned lev = k / 3u, dim = k % 3u;
        const float xv = (dim == 0u) ? x0 : ((dim == 1u) ? x1 : x2);
        const float t = xv * SCAL[lev];
        w[i] = t - floorf(t);
    }
    const float wa = w[0], wb = w[1], wc = w[2];
    const float qa = 1.f - wa, qb = 1.f - wb, qc = 1.f - wc;
    const float e0 = ((a0 * wa + a3 * qa) * wb + (a1 * wa + a2 * qa) * qb) * wc
                   + ((a4 * wa + a7 * qa) * wb + (a5 * wa + a6 * qa) * qb) * qc;
    const float e1 = ((b0 * wa + b3 * qa) * wb + (b1 * wa + b2 * qa) * qb) * wc
                   + ((b4 * wa + b7 * qa) * wb + (b5 * wa + b6 * qa) * qb) * qc;
    out[tid] = make_float2(e0, e1);
}

extern "C" void kernel_launch(void* const* d_in, const int* in_sizes, int n_in,
                              void* d_out, int out_size, void* d_ws, size_t ws_size,
                              hipStream_t stream) {
    const float* x   = (const float*)d_in[0];
    const float* tab = (const float*)d_in[1];
    float2* out = (float2*)d_out;

    const size_t need_pack = (size_t)NENT * 4u;                       // 32 MB
    const size_t need_full = need_pack + (size_t)NPTS * 16u * 8u;     // +128 MB

    if (ws_size >= need_pack) {
        unsigned* tp = (unsigned*)d_ws;
        pack_kernel<<<NENT / 4u / 256u, 256, 0, stream>>>(tab, tp);
        if (ws_size >= need_full) {
            float2* enc = (float2*)((char*)d_ws + need_pack);
            gather_kernel<false><<<16 * 4096, 256, 0, stream>>>(x, tp, enc);
            transpose_kernel<<<NPTS / 256u, 256, 0, stream>>>(enc, (float4*)d_out);
        } else {
            gather_kernel<true><<<16 * 4096, 256, 0, stream>>>(x, tp, out);
        }
    } else {
        hashenc_fallback<<<NPTS * 16u / 256u, 256, 0, stream>>>(x, tab, out);
    }
}

// Round 4
// 528.098 us; speedup vs baseline: 3.9455x; 1.3790x over previous
//
#include <hip/hip_runtime.h>
#include <hip/hip_fp16.h>

#define TS 524288u
#define NENT (TS * 16u)    // 8388608 entries per feature row
#define FSTR NENT
#define NPTS 1048576u
#define P1 2654435761u
#define P2 805459861u
#define DMAXL 5            // dense-cell levels 0..5

// SCALINGS = floor(16 * growth^l), growth = 2^(7/15). All exact integers.
__device__ const float SCAL[16] = {
    16.f, 22.f, 30.f, 42.f, 58.f, 80.f, 111.f, 153.f,
    212.f, 294.f, 406.f, 561.f, 776.f, 1072.f, 1482.f, 2048.f
};
// cumulative cell counts R^3 for levels 0..5 (R = 16,22,30,42,58,80)
__device__ const unsigned CCUM[6] = {4096u, 14744u, 41744u, 115832u, 310944u, 822944u};
// cumulative vertex counts (R+1)^3 for levels 0..5
__device__ const unsigned VCUM[6] = {4913u, 17080u, 46871u, 126378u, 331757u, 863198u};
// uint offsets of each level's cell-block region (8 uints per cell)
__device__ const unsigned DBASE[6] = {0u, 32768u, 117952u, 333952u, 926656u, 2487552u};
// uint offsets of each level's vertex region
__device__ const unsigned VBASE[6] = {0u, 4913u, 17080u, 46871u, 126378u, 331757u};

#define NCELLS 822944u
#define NVERTS 863198u
#define DNB    26334208u   // dense cell bytes  (822944*32)
#define DVB    3452792u    // dense vertex bytes (863198*4)

// fp32 -> bf16 round-to-nearest-even
__device__ inline unsigned bfp(float f) {
    unsigned u = __float_as_uint(f);
    return (u + 0x7FFFu + ((u >> 16) & 1u)) >> 16;
}
__device__ inline float blo(unsigned g) { return __uint_as_float(g << 16); }
__device__ inline float bhi(unsigned g) { return __uint_as_float(g & 0xFFFF0000u); }

// ---- pass 1: pack two fp32 feature rows into bf16x2 (4B/entry) ----
__global__ __launch_bounds__(256) void pack_kernel(
    const float* __restrict__ tab, unsigned* __restrict__ tp)
{
    const unsigned i = (blockIdx.x * 256u + threadIdx.x) * 4u;
    const float4 a = *reinterpret_cast<const float4*>(tab + i);
    const float4 b = *reinterpret_cast<const float4*>(tab + i + FSTR);
    uint4 r;
    r.x = bfp(a.x) | (bfp(b.x) << 16);
    r.y = bfp(a.y) | (bfp(b.y) << 16);
    r.z = bfp(a.z) | (bfp(b.z) << 16);
    r.w = bfp(a.w) | (bfp(b.w) << 16);
    *reinterpret_cast<uint4*>(tp + i) = r;
}

// ---- pass 1b: dense vertex arrays for levels 0..5 (one gather per vertex) ----
__global__ __launch_bounds__(256) void vbuild_kernel(
    const unsigned* __restrict__ tp, unsigned* __restrict__ dv)
{
    const unsigned t = blockIdx.x * 256u + threadIdx.x;
    if (t >= NVERTS) return;
    unsigned lv = 0, base = 0;
#pragma unroll
    for (int l = 0; l < DMAXL; ++l)
        if (t >= VCUM[l]) { lv = l + 1; base = VCUM[l]; }
    const unsigned vid = t - base;
    const unsigned Rp = (unsigned)SCAL[lv] + 1u;     // R+1
    const unsigned i = vid % Rp;
    const unsigned r1 = vid / Rp;
    const unsigned j = r1 % Rp;
    const unsigned k = r1 / Rp;
    const unsigned h = ((i ^ (j * P1) ^ (k * P2)) & (TS - 1u)) + lv * TS;
    dv[VBASE[lv] + vid] = tp[h];
}

// ---- pass 1c: assemble 32B cell blocks from dense vertices (coalesced-ish) ----
__global__ __launch_bounds__(256) void cbuild_kernel(
    const unsigned* __restrict__ dv, unsigned* __restrict__ dn)
{
    const unsigned t = blockIdx.x * 256u + threadIdx.x;
    if (t >= NCELLS) return;
    unsigned lv = 0, base = 0;
#pragma unroll
    for (int l = 0; l < DMAXL; ++l)
        if (t >= CCUM[l]) { lv = l + 1; base = CCUM[l]; }
    const unsigned cid = t - base;
    const unsigned R = (unsigned)SCAL[lv];
    const unsigned Rp = R + 1u;
    const unsigned B0 = cid % R;
    const unsigned r1 = cid / R;
    const unsigned B1 = r1 % R;
    const unsigned B2 = r1 / R;
    const unsigned* v = dv + VBASE[lv];
    const unsigned vb = (B2 * Rp + B1) * Rp + B0;   // vertex (B0,B1,B2)
    const unsigned sy = Rp, sz = Rp * Rp;
    // word order = SEL rows: (A,A,A),(A,A,B),(A,B,A),(B,A,A),(A,B,B),(B,A,B),(B,B,A),(B,B,B); A=B+1
    const unsigned w0 = v[vb + 1u + sy + sz];
    const unsigned w1 = v[vb + 1u + sy];
    const unsigned w2 = v[vb + 1u + sz];
    const unsigned w3 = v[vb + sy + sz];
    const unsigned w4 = v[vb + 1u];
    const unsigned w5 = v[vb + sy];
    const unsigned w6 = v[vb + sz];
    const unsigned w7 = v[vb];
    uint4* dst = reinterpret_cast<uint4*>(dn + DBASE[lv] + cid * 8u);
    dst[0] = make_uint4(w0, w1, w2, w3);
    dst[1] = make_uint4(w4, w5, w6, w7);
}

// ---- pass 2: gather + trilerp. One block = 256 points at ONE level. ----
// DENSE>=0: levels 0..DENSE read 32B cell blocks; others do 8 hashed gathers.
template <int DENSE>
__global__ __launch_bounds__(256) void gather_kernel(
    const float* __restrict__ x,
    const unsigned* __restrict__ tp,
    const unsigned* __restrict__ dn,
    __half2* __restrict__ dst)
{
    const unsigned lv = blockIdx.x >> 12;          // 0..15, uniform per block
    const unsigned n  = (blockIdx.x & 4095u) * 256u + threadIdx.x;

    const float x0 = x[3u * n + 0u];
    const float x1 = x[3u * n + 1u];
    const float x2 = x[3u * n + 2u];

    const float S = SCAL[lv];
    const float s0 = x0 * S, s1 = x1 * S, s2 = x2 * S;
    const unsigned m = TS - 1u;
    const unsigned tbase = lv * TS;

    unsigned g0, g1, g2, g3, g4, g5, g6, g7;

    if ((int)lv <= DENSE) {
        const float f0 = floorf(s0), f1 = floorf(s1), f2 = floorf(s2);
        const unsigned B0 = (unsigned)(int)f0;
        const unsigned B1 = (unsigned)(int)f1;
        const unsigned B2 = (unsigned)(int)f2;
        const unsigned R = (unsigned)S;            // SCAL entries are exact ints
        const unsigned cid = (B2 * R + B1) * R + B0;
        const uint4* blk = reinterpret_cast<const uint4*>(dn + DBASE[lv] + cid * 8u);
        const uint4 lo = blk[0];
        const uint4 hi = blk[1];
        g0 = lo.x; g1 = lo.y; g2 = lo.z; g3 = lo.w;
        g4 = hi.x; g5 = hi.y; g6 = hi.z; g7 = hi.w;
        // rare: s exactly integer -> ceil==floor, cell block (f,f+1) is wrong.
        const bool ex = (s0 == f0) | (s1 == f1) | (s2 == f2);
        if (__builtin_expect(__any(ex), 0)) {
            if (ex) {
                const unsigned A0 = (unsigned)(int)ceilf(s0);
                const unsigned a1 = (unsigned)(int)ceilf(s1) * P1, b1 = B1 * P1;
                const unsigned a2 = (unsigned)(int)ceilf(s2) * P2, b2 = B2 * P2;
                g0 = tp[((A0 ^ a1 ^ a2) & m) + tbase];
                g1 = tp[((A0 ^ a1 ^ b2) & m) + tbase];
                g2 = tp[((A0 ^ b1 ^ a2) & m) + tbase];
                g3 = tp[((B0 ^ a1 ^ a2) & m) + tbase];
                g4 = tp[((A0 ^ b1 ^ b2) & m) + tbase];
                g5 = tp[((B0 ^ a1 ^ b2) & m) + tbase];
                g6 = tp[((B0 ^ b1 ^ a2) & m) + tbase];
                g7 = tp[((B0 ^ b1 ^ b2) & m) + tbase];
            }
        }
    } else {
        const unsigned A0 = (unsigned)(int)ceilf(s0);
        const unsigned B0 = (unsigned)(int)floorf(s0);
        const unsigned a1 = (unsigned)(int)ceilf(s1) * P1;
        const unsigned b1 = (unsigned)(int)floorf(s1) * P1;
        const unsigned a2 = (unsigned)(int)ceilf(s2) * P2;
        const unsigned b2 = (unsigned)(int)floorf(s2) * P2;
        g0 = tp[((A0 ^ a1 ^ a2) & m) + tbase];
        g1 = tp[((A0 ^ a1 ^ b2) & m) + tbase];
        g2 = tp[((A0 ^ b1 ^ a2) & m) + tbase];
        g3 = tp[((B0 ^ a1 ^ a2) & m) + tbase];
        g4 = tp[((A0 ^ b1 ^ b2) & m) + tbase];
        g5 = tp[((B0 ^ a1 ^ b2) & m) + tbase];
        g6 = tp[((B0 ^ b1 ^ a2) & m) + tbase];
        g7 = tp[((B0 ^ b1 ^ b2) & m) + tbase];
    }

    // weights: reference reshape quirk. po[n,i,l] = frac[n,(i*16+l)/3,(i*16+l)%3]
    float w[3];
#pragma unroll
    for (int i = 0; i < 3; ++i) {
        const unsigned k = lv + 16u * i;           // block-uniform
        const unsigned lev = k / 3u, dim = k % 3u;
        const float xv = (dim == 0u) ? x0 : ((dim == 1u) ? x1 : x2);
        const float t = xv * SCAL[lev];
        w[i] = t - floorf(t);
    }
    const float wa = w[0], wb = w[1], wc = w[2];
    const float qa = 1.f - wa, qb = 1.f - wb, qc = 1.f - wc;

    const float e0 = ((blo(g0) * wa + blo(g3) * qa) * wb + (blo(g1) * wa + blo(g2) * qa) * qb) * wc
                   + ((blo(g4) * wa + blo(g7) * qa) * wb + (blo(g5) * wa + blo(g6) * qa) * qb) * qc;
    const float e1 = ((bhi(g0) * wa + bhi(g3) * qa) * wb + (bhi(g1) * wa + bhi(g2) * qa) * qb) * wc
                   + ((bhi(g4) * wa + bhi(g7) * qa) * wb + (bhi(g5) * wa + bhi(g6) * qa) * qb) * qc;

    dst[lv * NPTS + n] = __floats2half2_rn(e0, e1);
}

// ---- pass 3: transpose enc[lv][n] (half2) -> out[n][lv] (fp32) ----
__global__ __launch_bounds__(256) void transpose_kernel(
    const __half2* __restrict__ enc, float4* __restrict__ out)
{
    const unsigned n = blockIdx.x * 256u + threadIdx.x;
    float2 v[16];
#pragma unroll
    for (int lv = 0; lv < 16; ++lv) v[lv] = __half22float2(enc[lv * NPTS + n]);
#pragma unroll
    for (int k = 0; k < 8; ++k)
        out[n * 8u + k] = make_float4(v[2 * k].x, v[2 * k].y, v[2 * k + 1].x, v[2 * k + 1].y);
}

// ---- last-resort fallback: no workspace (round-1 kernel) ----
__global__ __launch_bounds__(256) void hashenc_fallback(
    const float* __restrict__ x,
    const float* __restrict__ tab,
    float2* __restrict__ out)
{
    const unsigned tid = blockIdx.x * 256u + threadIdx.x;
    const unsigned n = tid >> 4;
    const unsigned l = tid & 15u;
    const float x0 = x[3u * n], x1 = x[3u * n + 1u], x2 = x[3u * n + 2u];
    const float S = SCAL[l];
    const float s0 = x0 * S, s1 = x1 * S, s2 = x2 * S;
    const unsigned A0 = (unsigned)(int)ceilf(s0);
    const unsigned B0 = (unsigned)(int)floorf(s0);
    const unsigned a1 = (unsigned)(int)ceilf(s1) * P1;
    const unsigned b1 = (unsigned)(int)floorf(s1) * P1;
    const unsigned a2 = (unsigned)(int)ceilf(s2) * P2;
    const unsigned b2 = (unsigned)(int)floorf(s2) * P2;
    const unsigned m = TS - 1u;
    const unsigned base = l * TS;
    const unsigned i0 = ((A0 ^ a1 ^ a2) & m) + base;
    const unsigned i1 = ((A0 ^ a1 ^ b2) & m) + base;
    const unsigned i2 = ((A0 ^ b1 ^ a2) & m) + base;
    const unsigned i3 = ((B0 ^ a1 ^ a2) & m) + base;
    const unsigned i4 = ((A0 ^ b1 ^ b2) & m) + base;
    const unsigned i5 = ((B0 ^ a1 ^ b2) & m) + base;
    const unsigned i6 = ((B0 ^ b1 ^ a2) & m) + base;
    const unsigned i7 = ((B0 ^ b1 ^ b2) & m) + base;
    const float a0v = tab[i0], a1v = tab[i1], a2v = tab[i2], a3v = tab[i3];
    const float a4v = tab[i4], a5v = tab[i5], a6v = tab[i6], a7v = tab[i7];
    const float b0v = tab[i0 + FSTR], b1v = tab[i1 + FSTR], b2v = tab[i2 + FSTR], b3v = tab[i3 + FSTR];
    const float b4v = tab[i4 + FSTR], b5v = tab[i5 + FSTR], b6v = tab[i6 + FSTR], b7v = tab[i7 + FSTR];
    float w[3];
#pragma unroll
    for (int i = 0; i < 3; ++i) {
        const unsigned k = l + 16u * i;
        const unsigned lev = k / 3u, dim = k % 3u;
        const float xv = (dim == 0u) ? x0 : ((dim == 1u) ? x1 : x2);
        const float t = xv * SCAL[lev];
        w[i] = t - floorf(t);
    }
    const float wa = w[0], wb = w[1], wc = w[2];
    const float qa = 1.f - wa, qb = 1.f - wb, qc = 1.f - wc;
    const float e0 = ((a0v * wa + a3v * qa) * wb + (a1v * wa + a2v * qa) * qb) * wc
                   + ((a4v * wa + a7v * qa) * wb + (a5v * wa + a6v * qa) * qb) * qc;
    const float e1 = ((b0v * wa + b3v * qa) * wb + (b1v * wa + b2v * qa) * qb) * wc
                   + ((b4v * wa + b7v * qa) * wb + (b5v * wa + b6v * qa) * qb) * qc;
    out[tid] = make_float2(e0, e1);
}

extern "C" void kernel_launch(void* const* d_in, const int* in_sizes, int n_in,
                              void* d_out, int out_size, void* d_ws, size_t ws_size,
                              hipStream_t stream) {
    const float* x   = (const float*)d_in[0];
    const float* tab = (const float*)d_in[1];
    char* ws = (char*)d_ws;

    const size_t packB = (size_t)NENT * 4u;            // 32 MB
    const size_t scrB  = (size_t)NPTS * 16u * 4u;      // 64 MB half2 scratch
    const size_t need_dense = packB + (size_t)DNB + (size_t)DVB + scrB;  // ~126 MB
    const size_t need_plain = packB + scrB;                              // ~96 MB

    if (ws_size >= need_dense) {
        unsigned* tp = (unsigned*)ws;
        unsigned* dn = (unsigned*)(ws + packB);
        unsigned* dv = (unsigned*)(ws + packB + DNB);
        __half2*  sc = (__half2*)(ws + packB + DNB + DVB);
        pack_kernel<<<NENT / 4u / 256u, 256, 0, stream>>>(tab, tp);
        vbuild_kernel<<<(NVERTS + 255u) / 256u, 256, 0, stream>>>(tp, dv);
        cbuild_kernel<<<(NCELLS + 255u) / 256u, 256, 0, stream>>>(dv, dn);
        gather_kernel<DMAXL><<<16 * 4096, 256, 0, stream>>>(x, tp, dn, sc);
        transpose_kernel<<<NPTS / 256u, 256, 0, stream>>>(sc, (float4*)d_out);
    } else if (ws_size >= need_plain) {
        unsigned* tp = (unsigned*)ws;
        __half2*  sc = (__half2*)(ws + packB);
        pack_kernel<<<NENT / 4u / 256u, 256, 0, stream>>>(tab, tp);
        gather_kernel<-1><<<16 * 4096, 256, 0, stream>>>(x, tp, tp, sc);
        transpose_kernel<<<NPTS / 256u, 256, 0, stream>>>(sc, (float4*)d_out);
    } else {
        hashenc_fallback<<<NPTS * 16u / 256u, 256, 0, stream>>>(x, tab, (float2*)d_out);
    }
}